// Round 1
// baseline (764.905 us; speedup 1.0000x reference)
//
#include <hip/hip_runtime.h>
#include <math.h>

// StructNDeconv2D: depthwise conv_transpose2d(stride=2,pad=1,dil=1,K=3) of
// (cd*d), cd, ones with softplus'd weights, then pointwise normalize.
//
// Direct gather form: out[oy,ox] = sum_k w[ky,kx] * x[(oy+1-ky)/2, (ox+1-kx)/2]
// with oy+1-ky even. Parity trick (verified index algebra):
//   tap A: i = (o+1)>>1, kernel row = odd(o) ? 0 : 1, always active
//   tap B: i = o>>1,     kernel row = 2,               active iff odd(o)
// All taps are always in-bounds for o in [0,510] -> no boundary checks.

constexpr int B_ = 8, C_ = 32, IH = 256, IW = 256, OH = 511, OW = 511;
constexpr unsigned TOTAL = (unsigned)B_ * C_ * OH * OW;  // 66,846,976
constexpr float EPS = 1e-20f;

__global__ void softplus_k(const float* __restrict__ w, float* __restrict__ sw) {
    int i = blockIdx.x * blockDim.x + threadIdx.x;
    if (i < C_ * 9) {
        float x = w[i];
        // numerically stable softplus
        sw[i] = (x > 0.f) ? (x + log1pf(expf(-x))) : log1pf(expf(x));
    }
}

__global__ __launch_bounds__(256) void deconv_k(
    const float* __restrict__ d, const float* __restrict__ cd,
    const float* __restrict__ sw, const float* __restrict__ bias,
    float* __restrict__ out) {
    unsigned idx = blockIdx.x * blockDim.x + threadIdx.x;
    if (idx >= TOTAL) return;

    unsigned ox = idx % OW;
    unsigned t  = idx / OW;
    unsigned oy = t % OH;
    unsigned bc = t / OH;
    unsigned c  = bc & (C_ - 1);
    const float* __restrict__ swc = sw + c * 9;

    const bool oddy = oy & 1u, oddx = ox & 1u;
    // Tap indices (branchless; identical expressions for both parities)
    const unsigned iyA = (oy + 1) >> 1, iyB = oy >> 1;
    const unsigned ixA = (ox + 1) >> 1, ixB = ox >> 1;
    const int kyA = oddy ? 0 : 1;
    const int kxA = oddx ? 0 : 1;
    const float myB = oddy ? 1.f : 0.f;  // B-row tap only active on odd oy
    const float mxB = oddx ? 1.f : 0.f;  // B-col tap only active on odd ox

    const float wAA = swc[kyA * 3 + kxA];
    const float wAB = swc[kyA * 3 + 2] * mxB;
    const float wBA = swc[6 + kxA] * myB;
    const float wBB = swc[8] * myB * mxB;

    const unsigned base = bc * (IH * IW);
    const unsigned oAA = base + iyA * IW + ixA;
    const unsigned oAB = base + iyA * IW + ixB;
    const unsigned oBA = base + iyB * IW + ixA;
    const unsigned oBB = base + iyB * IW + ixB;

    const float cAA = cd[oAA], cAB = cd[oAB], cBA = cd[oBA], cBB = cd[oBB];
    const float dAA = d[oAA],  dAB = d[oAB],  dBA = d[oBA],  dBB = d[oBB];

    const float den = wAA * cAA + wAB * cAB + wBA * cBA + wBB * cBB;
    const float nom = wAA * cAA * dAA + wAB * cAB * dAB +
                      wBA * cBA * dBA + wBB * cBB * dBB;
    const float cds = wAA + wAB + wBA + wBB;  // deconv of ones: no loads needed

    out[idx]         = nom / (den + EPS) + bias[c];
    out[TOTAL + idx] = den / (cds + EPS);
}

extern "C" void kernel_launch(void* const* d_in, const int* in_sizes, int n_in,
                              void* d_out, int out_size, void* d_ws, size_t ws_size,
                              hipStream_t stream) {
    const float* d    = (const float*)d_in[0];
    const float* cd   = (const float*)d_in[1];
    const float* w    = (const float*)d_in[2];
    const float* bias = (const float*)d_in[3];
    float* out = (float*)d_out;
    float* sw  = (float*)d_ws;  // 288 floats of softplus'd weights

    softplus_k<<<2, 256, 0, stream>>>(w, sw);
    const unsigned nblk = (TOTAL + 255u) / 256u;
    deconv_k<<<nblk, 256, 0, stream>>>(d, cd, sw, bias, out);
}